// Round 11
// baseline (152.179 us; speedup 1.0000x reference)
//
#include <hip/hip_runtime.h>
#include <stdint.h>

#define UU 512
#define NHEAD 8
#define NB 8
#define NXX 1024
#define NYY 1024
#define SCALE_F 0.125f   // 1/sqrt(64)

typedef __bf16 bf16x8 __attribute__((ext_vector_type(8)));
typedef float f32x4 __attribute__((ext_vector_type(4)));
typedef unsigned short us4 __attribute__((ext_vector_type(4)));

__device__ __forceinline__ unsigned short f2bf(float f) {
  union { float f; uint32_t u; } v; v.f = f;
  return (unsigned short)((v.u + 0x7FFFu + ((v.u >> 16) & 1u)) >> 16);
}

// ---------------------------------------------------------------------------
// Mask dtype probe: u8 bool -> nonzero bytes at p%4==1; i32/f32 -> zero there.
__global__ void detect_mask(const unsigned char* __restrict__ m, int* __restrict__ det) {
  int t = threadIdx.x;
  int c1 = 0;
  for (int q = t; q < 16384; q += 256) c1 |= m[q * 4 + 1];
  if (c1) atomicOr(&det[0], 1);
}

// ---------------------------------------------------------------------------
// prep: blocks 0..127 pack W -> bf16 fragment-order Wp[ub][kb][lane][8].
// Blocks 128..2175: pack mask -> mbt[b][mt(32m)][n] u32: bit p = mask[b][n][mt*32+p].
__global__ void prep_kernel(const float* __restrict__ W, unsigned short* __restrict__ Wp,
                            const void* __restrict__ maskp, const int* __restrict__ det,
                            unsigned int* __restrict__ mbt) {
  __shared__ unsigned short sm[256];
  int blk = blockIdx.x, t = threadIdx.x;
  if (blk < 128) {
    int s = blk * 256 + t;
    int ub = s >> 10, kb = (s >> 6) & 15, l = s & 63;
    int u = ub * 16 + (l & 15), k = kb * 32 + (l >> 4) * 8;
    const float* src = W + (size_t)u * UU + k;
    float4 a = *(const float4*)src;
    float4 bq = *(const float4*)(src + 4);
    uint4 o;
    o.x = (unsigned)f2bf(a.x) | ((unsigned)f2bf(a.y) << 16);
    o.y = (unsigned)f2bf(a.z) | ((unsigned)f2bf(a.w) << 16);
    o.z = (unsigned)f2bf(bq.x) | ((unsigned)f2bf(bq.y) << 16);
    o.w = (unsigned)f2bf(bq.z) | ((unsigned)f2bf(bq.w) << 16);
    *(uint4*)(Wp + (size_t)s * 8) = o;
    return;
  }
  int pb = blk - 128;                         // 0..2047; block covers 4 n-rows
  size_t g = (size_t)pb * 256 + t;            // 16-element group (row t>>6, m-grp t&63)
  unsigned int bm = 0;
  if (det[0]) {                               // u8 bool elements
    uint4 v = *(const uint4*)((const unsigned char*)maskp + g * 16);
    unsigned int wd[4] = {v.x, v.y, v.z, v.w};
#pragma unroll
    for (int j = 0; j < 16; j++)
      bm |= (((wd[j >> 2] >> ((j & 3) * 8)) & 0xffu) != 0u) << j;
  } else {                                    // 4-byte elements (i32 or f32)
    const unsigned int* mp = (const unsigned int*)maskp + g * 16;
#pragma unroll
    for (int q = 0; q < 4; q++) {
      uint4 v = *(const uint4*)(mp + q * 4);
      unsigned int wd[4] = {v.x, v.y, v.z, v.w};
#pragma unroll
      for (int j = 0; j < 4; j++)
        bm |= (wd[j] != 0u) << (q * 4 + j);
    }
  }
  sm[t] = (unsigned short)bm;
  __syncthreads();
  if (t < 128) {
    int row = t >> 5, mt = t & 31;
    unsigned int w32 = (unsigned)sm[row * 64 + mt * 2]
                     | ((unsigned)sm[row * 64 + mt * 2 + 1] << 16);
    int gr = pb * 4 + row;                    // global row 0..8191
    int b = gr >> 10, n = gr & 1023;
    mbt[(((size_t)b * 32 + mt) << 10) + n] = w32;
  }
}

// ---------------------------------------------------------------------------
// conv_x: pcx[b][q16][h][kb][lane][8] = x-side conv in score-fragment layout.
// Block = (b, 64 n-rows, 256 u), grid 256. (R9-verified structure, x only.)
__global__ __launch_bounds__(256, 2) void conv_x(
    const float* __restrict__ x, const unsigned short* __restrict__ Wp,
    unsigned short* __restrict__ pcx) {
  __shared__ unsigned short xs[64 * 512];    // 64 KB
  int fl = blockIdx.x;
  int b = fl & 7, nt = (fl >> 3) & 15, ut = fl >> 7;
  int n0 = nt * 64;
  int t = threadIdx.x, w = t >> 6, l = t & 63;
  int lane_m = l & 15, lane_g = l >> 4;

  {
    int cq = (t & 15) * 4;
    int i2b = (t >> 4) * 2;
    const float* gb = x + (size_t)b * UU * NXX + n0 + cq;
#pragma unroll
    for (int it = 0; it < 16; it++) {
      int i2 = i2b + it * 32;
      float4 va = *(const float4*)(gb + (size_t)i2 * NXX);
      float4 vb = *(const float4*)(gb + (size_t)(i2 + 1) * NXX);
      float fa[4] = {va.x, va.y, va.z, va.w};
      float fb[4] = {vb.x, vb.y, vb.z, vb.w};
#pragma unroll
      for (int j = 0; j < 4; j++) {
        int n = cq + j;
        unsigned int pk = (unsigned)f2bf(fa[j]) | ((unsigned)f2bf(fb[j]) << 16);
        int e = n * 512 + (i2 ^ ((n & 7) << 3));
        *(unsigned int*)&xs[e] = pk;
      }
    }
  }
  __syncthreads();

  int u0 = ut * 256 + w * 64;
  int ub0 = u0 >> 4;
  const unsigned short* wb0 = Wp + (size_t)l * 8;
  f32x4 acc[4][4] = {};
  bf16x8 aA[4], aB[4], bA[4], bB[4];

#define LOADW(Adst, Bdst, KB) do {                                            \
    _Pragma("unroll") for (int tu = 0; tu < 4; tu++)                          \
      Adst[tu] = *(const bf16x8*)(wb0 + ((size_t)(ub0 + tu) * 16 + (KB)) * 512); \
    _Pragma("unroll") for (int tn = 0; tn < 4; tn++) {                        \
      int nl_ = tn * 16 + lane_m;                                             \
      int ka_ = (KB) * 32 + lane_g * 8;                                       \
      Bdst[tn] = *(const bf16x8*)&xs[nl_ * 512 + (ka_ ^ ((nl_ & 7) << 3))];   \
    }                                                                         \
  } while (0)
#define DOMFMA(Ab, Bb) do {                                                   \
    _Pragma("unroll") for (int tn = 0; tn < 4; tn++)                          \
    _Pragma("unroll") for (int tu = 0; tu < 4; tu++)                          \
      acc[tn][tu] = __builtin_amdgcn_mfma_f32_16x16x32_bf16(Ab[tu], Bb[tn], acc[tn][tu], 0, 0, 0); \
  } while (0)

  LOADW(aA, bA, 0);
#pragma unroll
  for (int kp = 0; kp < 8; kp++) {
    LOADW(aB, bB, 2 * kp + 1);
    DOMFMA(aA, bA);
    if (kp < 7) LOADW(aA, bA, 2 * kp + 2);
    DOMFMA(aB, bB);
  }
#undef LOADW
#undef DOMFMA

  unsigned short* ob = pcx + (size_t)b * 64 * 8 * 2 * 512;
  int h = u0 >> 6;                            // = ut*4 + w
  int e0 = 4 * (lane_g & 1);
#pragma unroll
  for (int tn = 0; tn < 4; tn++)
#pragma unroll
    for (int tu = 0; tu < 4; tu++) {
      int q16 = nt * 4 + tn;
      int kb = tu >> 1;
      int g = (2 * tu + (lane_g >> 1)) & 3;
      size_t slot = ((size_t)q16 * 8 + h) * 2 + kb;
      us4 pk;
      pk.x = f2bf(acc[tn][tu][0]); pk.y = f2bf(acc[tn][tu][1]);
      pk.z = f2bf(acc[tn][tu][2]); pk.w = f2bf(acc[tn][tu][3]);
      *(us4*)(ob + slot * 512 + (g * 16 + lane_m) * 8 + e0) = pk;
    }
}

// ---------------------------------------------------------------------------
// conv_score: block (b, 32 m-rows). Phase 1: conv y-tile (A=Wp, B=yin LDS),
// write result to LDS yfr in score-fragment-packed layout. Phase 2: loop
// nt=0..15 over x-side pcx: score MFMA, relu*maskbit accumulate. B-frags are
// LDS-resident and nt-invariant; A-frags = contiguous 1KB wave-loads.
__global__ __launch_bounds__(256, 2) void conv_score(
    const float* __restrict__ y, const unsigned short* __restrict__ Wp,
    const unsigned short* __restrict__ pcx, const unsigned int* __restrict__ mbt,
    float* __restrict__ part) {
  __shared__ unsigned short yin[32 * 512];   // 32 KB staged y-input
  __shared__ unsigned short yfr[32 * 512];   // 32 KB conv-out, frag-packed
  __shared__ unsigned int mrow[1024];        // 4 KB mask u32 rows
  __shared__ float red[4][4];
  int fl = blockIdx.x;
  int b = fl & 7, mt = fl >> 3;              // mt 0..31
  int m0 = mt * 32;
  int t = threadIdx.x, w = t >> 6, l = t & 63;
  int lane_m = l & 15, lane_g = l >> 4;

  // ---- stage y-input: [32m][512k] bf16, pair-packed, granule swizzle
  {
    int cq = (t & 7) * 4;
    int i2b = (t >> 3) * 2;
    const float* gb = y + (size_t)b * UU * NXX + m0 + cq;
#pragma unroll
    for (int it = 0; it < 8; it++) {
      int i2 = i2b + it * 64;
      float4 va = *(const float4*)(gb + (size_t)i2 * NXX);
      float4 vb = *(const float4*)(gb + (size_t)(i2 + 1) * NXX);
      float fa[4] = {va.x, va.y, va.z, va.w};
      float fb[4] = {vb.x, vb.y, vb.z, vb.w};
#pragma unroll
      for (int j = 0; j < 4; j++) {
        int n = cq + j;
        unsigned int pk = (unsigned)f2bf(fa[j]) | ((unsigned)f2bf(fb[j]) << 16);
        int e = n * 512 + (i2 ^ ((n & 7) << 3));
        *(unsigned int*)&yin[e] = pk;
      }
    }
  }
  // ---- stage mask rows + local popcount
  unsigned int cl;
  {
    uint4 mv = *(const uint4*)(mbt + (((size_t)b * 32 + mt) << 10) + t * 4);
    *(uint4*)&mrow[t * 4] = mv;
    cl = __popc(mv.x) + __popc(mv.y) + __popc(mv.z) + __popc(mv.w);
  }
  for (int s = 1; s < 64; s <<= 1) cl += __shfl_xor(cl, s);
  if (l == 0) red[w][2] = (float)cl;
  __syncthreads();

  // ---- phase 1: conv y-tile. Wave w owns u = w*128..+127 (heads 2w, 2w+1),
  // two 64-u halves to bound register pressure.
  const unsigned short* wb0 = Wp + (size_t)l * 8;
#pragma unroll
  for (int half = 0; half < 2; half++) {
    int ub0 = w * 8 + half * 4;
    f32x4 acc[2][4] = {};
    bf16x8 aA[4], aB[4], bA[2], bB[2];
#define LOADW2(Adst, Bdst, KB) do {                                           \
    _Pragma("unroll") for (int tu = 0; tu < 4; tu++)                          \
      Adst[tu] = *(const bf16x8*)(wb0 + ((size_t)(ub0 + tu) * 16 + (KB)) * 512); \
    _Pragma("unroll") for (int tn = 0; tn < 2; tn++) {                        \
      int nl_ = tn * 16 + lane_m;                                             \
      int ka_ = (KB) * 32 + lane_g * 8;                                       \
      Bdst[tn] = *(const bf16x8*)&yin[nl_ * 512 + (ka_ ^ ((nl_ & 7) << 3))];  \
    }                                                                         \
  } while (0)
#define DOMFMA2(Ab, Bb) do {                                                  \
    _Pragma("unroll") for (int tn = 0; tn < 2; tn++)                          \
    _Pragma("unroll") for (int tu = 0; tu < 4; tu++)                          \
      acc[tn][tu] = __builtin_amdgcn_mfma_f32_16x16x32_bf16(Ab[tu], Bb[tn], acc[tn][tu], 0, 0, 0); \
  } while (0)
    LOADW2(aA, bA, 0);
#pragma unroll
    for (int kp = 0; kp < 8; kp++) {
      LOADW2(aB, bB, 2 * kp + 1);
      DOMFMA2(aA, bA);
      if (kp < 7) LOADW2(aA, bA, 2 * kp + 2);
      DOMFMA2(aB, bB);
    }
#undef LOADW2
#undef DOMFMA2
    // write conv-out frags to LDS (score-B-frag layout)
    int h = w * 2 + half;
    int e0 = 4 * (lane_g & 1);
#pragma unroll
    for (int tn = 0; tn < 2; tn++)
#pragma unroll
      for (int tu = 0; tu < 4; tu++) {
        int kb = tu >> 1;
        int g = (2 * tu + (lane_g >> 1)) & 3;
        int slot = (tn * 8 + h) * 2 + kb;
        us4 pk;
        pk.x = f2bf(acc[tn][tu][0]); pk.y = f2bf(acc[tn][tu][1]);
        pk.z = f2bf(acc[tn][tu][2]); pk.w = f2bf(acc[tn][tu][3]);
        *(us4*)&yfr[slot * 512 + (g * 16 + lane_m) * 8 + e0] = pk;
      }
  }
  __syncthreads();

  // ---- phase 2: score. B-frags LDS-resident (nt-invariant), A from pcx.
  int h0 = w * 2;
  bf16x8 bfr[2][2][2];                        // [hh][tm][kb]
#pragma unroll
  for (int hh = 0; hh < 2; hh++)
#pragma unroll
    for (int tm = 0; tm < 2; tm++)
#pragma unroll
      for (int kb = 0; kb < 2; kb++) {
        int slot = (tm * 8 + h0 + hh) * 2 + kb;
        bfr[hh][tm][kb] = *(const bf16x8*)&yfr[slot * 512 + l * 8];
      }
  const unsigned short* xpl = pcx + (size_t)b * 64 * 8 * 2 * 512 + (size_t)l * 8;
  float hsv[2] = {0.f, 0.f};
  for (int nt = 0; nt < 16; nt++) {
    bf16x8 afr[2][4][2];                      // [hh][tn][kb]
#pragma unroll
    for (int hh = 0; hh < 2; hh++)
#pragma unroll
      for (int tn = 0; tn < 4; tn++)
#pragma unroll
        for (int kb = 0; kb < 2; kb++)
          afr[hh][tn][kb] = *(const bf16x8*)(xpl +
              ((((size_t)(nt * 4 + tn)) * 8 + h0 + hh) * 2 + kb) * 512);
    unsigned int mwv[4][4];
#pragma unroll
    for (int tn = 0; tn < 4; tn++)
#pragma unroll
      for (int r = 0; r < 4; r++)
        mwv[tn][r] = mrow[nt * 64 + tn * 16 + 4 * lane_g + r] >> lane_m;
#pragma unroll
    for (int hh = 0; hh < 2; hh++)
#pragma unroll
      for (int tn = 0; tn < 4; tn++)
#pragma unroll
        for (int tm = 0; tm < 2; tm++) {
          f32x4 acc = {};
          acc = __builtin_amdgcn_mfma_f32_16x16x32_bf16(afr[hh][tn][0], bfr[hh][tm][0], acc, 0, 0, 0);
          acc = __builtin_amdgcn_mfma_f32_16x16x32_bf16(afr[hh][tn][1], bfr[hh][tm][1], acc, 0, 0, 0);
#pragma unroll
          for (int r = 0; r < 4; r++) {
            float v = acc[r];
            v = v > 0.f ? v : 0.f;
            hsv[hh] += ((mwv[tn][r] >> (tm * 16)) & 1u) ? v : 0.f;
          }
        }
  }
#pragma unroll
  for (int hh = 0; hh < 2; hh++) {
    float hs = hsv[hh];
    for (int s = 1; s < 64; s <<= 1) hs += __shfl_xor(hs, s);
    if (l == 0) red[w][hh] = hs;
  }
  __syncthreads();
  float* pb = part + (size_t)fl * 16;
  if (t < 8) pb[t] = red[t >> 1][t & 1];      // head h = t
  else if (t == 8) pb[8] = red[0][2] + red[1][2] + red[2][2] + red[3][2];
}

// ---------------------------------------------------------------------------
// One 64-thread block per b: sum part rows fl = mt*8 + b, mt 0..31.
__global__ void finalize(const float* __restrict__ part, const float* __restrict__ fcw,
                         const float* __restrict__ fcb, float* __restrict__ out) {
  int b = blockIdx.x, t = threadIdx.x;
  float v[9];
#pragma unroll
  for (int j = 0; j < 9; j++) v[j] = 0.f;
  if (t < 32) {
    const float* pb = part + (size_t)(t * 8 + b) * 16;
#pragma unroll
    for (int j = 0; j < 9; j++) v[j] = pb[j];
  }
#pragma unroll
  for (int j = 0; j < 9; j++) {
    float s = v[j];
    for (int ss = 1; ss < 64; ss <<= 1) s += __shfl_xor(s, ss);
    v[j] = s;
  }
  if (t == 0) {
    float s = 0.f;
#pragma unroll
    for (int h = 0; h < NHEAD; h++) s += v[h] * fcw[h];
    float cn = v[8];
    if (cn < 0.5f) cn = 1.f;
    out[b] = s * (SCALE_F / cn) + fcb[0];
  }
}

// ---------------------------------------------------------------------------
extern "C" void kernel_launch(void* const* d_in, const int* in_sizes, int n_in,
                              void* d_out, int out_size, void* d_ws, size_t ws_size,
                              hipStream_t stream) {
  const float* x = (const float*)d_in[0];
  const float* y = (const float*)d_in[1];
  const void* mask = d_in[2];
  const float* W = (const float*)d_in[3];
  const float* fcw = (const float*)d_in[4];
  const float* fcb = (const float*)d_in[5];
  float* out = (float*)d_out;
  char* ws = (char*)d_ws;

  unsigned short* pcx = (unsigned short*)ws;                 // x conv frag-packed, 8 MB
  unsigned short* Wp = (unsigned short*)(ws + (8u << 20));   // packed W bf16, 512 KB
  unsigned int* mbt = (unsigned int*)(ws + (8u << 20) + (512u << 10));  // 1 MB
  float* part = (float*)(ws + (8u << 20) + (1536u << 10));   // [256][16] f32, 16 KB
  int* det = (int*)(ws + (8u << 20) + (1552u << 10));        // 1 i32

  hipMemsetAsync(det, 0, 64, stream);
  detect_mask<<<1, 256, 0, stream>>>((const unsigned char*)mask, det);
  prep_kernel<<<2176, 256, 0, stream>>>(W, Wp, mask, det, mbt);
  conv_x<<<256, 256, 0, stream>>>(x, Wp, pcx);
  conv_score<<<256, 256, 0, stream>>>(y, Wp, pcx, mbt, part);
  finalize<<<NB, 64, 0, stream>>>(part, fcw, fcb, out);
}